// Round 8
// baseline (100.972 us; speedup 1.0000x reference)
//
#include <hip/hip_runtime.h>
#include <stdint.h>

// Problem constants (reference: B=8, N=16384, F=128, P=28)
#define FDIM  128
#define PDIM  28
#define MPTS  131072           // 8 * 16384 points
#define PSTR  4096             // f16 stride per p-slab: 4 fq * 2 kh * 32 f * 2 hi * 8 j

typedef _Float16 half8   __attribute__((ext_vector_type(8)));
typedef float    floatx16 __attribute__((ext_vector_type(16)));

// ---------------------------------------------------------------------------
// Prep: IF [F][P][P] fp32 -> IFt [28 p][4 fq][2 kh][32 fl][2 hi][8 j] f16.
// One (p, fq, kh) slab = 1024 B, contiguous & 1KB-aligned = EXACTLY one
// wave's B fragment for mfma_f32_32x32x16_f16:
//   B[k = hi*8 + j][n = fl] with k local = kh*16 + hi*8 + j (q), n = feature.
// q >= 28 zero-padded (kh=1,hi=1,j>=4).
// ---------------------------------------------------------------------------
__global__ __launch_bounds__(256) void prep_ift(const float* __restrict__ IF,
                                                _Float16* __restrict__ IFt) {
    int idx = blockIdx.x * 256 + threadIdx.x;     // 0 .. 28*4096-1
    int j   = idx & 7;
    int hi  = (idx >> 3) & 1;
    int fl  = (idx >> 4) & 31;
    int kh  = (idx >> 9) & 1;
    int fq  = (idx >> 10) & 3;
    int p   = idx >> 12;
    int q   = kh * 16 + hi * 8 + j;
    int f   = fq * 32 + fl;
    float v = (q < PDIM) ? IF[f * (PDIM * PDIM) + p * PDIM + q] : 0.0f;
    IFt[idx] = (_Float16)v;
}

// ---------------------------------------------------------------------------
// Main: C[m,f] = sum_{p,q} k0[m,p] * IF[f,p,q] * k1[m,q]
//
// ZERO LDS, ZERO BARRIERS. Change vs R7: nt=2 — wave tile 128 pts x 64 f.
// Each scaled A-fragment (k1f * k0, 4 v_pk_mul_f16) now feeds TWO MFMAs
// (the two fq slabs of the feature half), halving the VALU wall:
// per p: 4 loads (4KB) + 8 A-scalings (32 pk_mul) + 16 MFMAs.
//  - k1 A-fragments hoisted (p-invariant); k0 in-loop (4 expf/p, TRANS).
//  - B: 2-deep static prefetch rotation, 8 named half8 regs.
//  - 4 same-fh waves/block -> B slabs shared in L1; grid 512, all resident.
// acc[4][2] f32x16 (128) + k1f 32 + prefetch 32 + misc => ~210 VGPR
// -> 2 waves/SIMD; 8 independent acc chains/wave keep the matrix pipe full.
// ---------------------------------------------------------------------------
__global__ __launch_bounds__(256, 2) void feats_kernel(
    const float* __restrict__ x,       // [MPTS][2]
    const float* __restrict__ sigma,   // [1] log lengthscale
    const _Float16* __restrict__ IFt,  // [28][4][2][32][2][8] f16
    float* __restrict__ out)           // [MPTS][FDIM]
{
    const int tid   = threadIdx.x;
    const int lane  = tid & 63;
    const int wave  = tid >> 6;          // 0..3, stacked in m
    const int ln31  = lane & 31;
    const int hi    = lane >> 5;         // k-half-of-fragment select
    const int chunk = blockIdx.x >> 1;   // 512-point chunk (0..255)
    const int fh    = blockIdx.x & 1;    // feature half: fq = fh*2, fh*2+1

    const int mbase = chunk * 512 + wave * 128;

    const float ls    = __expf(sigma[0]);
    const float inv   = 0.5f / (ls * ls);
    const float gstep = 0.998f / 27.0f;

    // per-lane fragment base for fq = fh*2 (second slab at +1024 f16)
    const _Float16* gB = IFt + (fh * 2) * 1024 + ln31 * 16 + hi * 8;

    // ---- issue first two p-slabs' loads IMMEDIATELY ----
    // naming: b{A,B}{nt}{kh}; A = even p, B = odd p
    half8 bA00 = *(const half8*)(gB + 0 * PSTR);
    half8 bA01 = *(const half8*)(gB + 0 * PSTR + 512);
    half8 bA10 = *(const half8*)(gB + 0 * PSTR + 1024);
    half8 bA11 = *(const half8*)(gB + 0 * PSTR + 1536);
    half8 bB00 = *(const half8*)(gB + 1 * PSTR);
    half8 bB01 = *(const half8*)(gB + 1 * PSTR + 512);
    half8 bB10 = *(const half8*)(gB + 1 * PSTR + 1024);
    half8 bB11 = *(const half8*)(gB + 1 * PSTR + 1536);

    // ---- A-side k1 fragments (p-invariant) + x0, in registers ----
    // A layout (32x32x16): A[m = lane&31][k = hi*8 + j]; k local = q.
    // Fragment kh covers q = kh*16 + hi*8 + j. q>=28: finite garbage * B=0.
    half8 k1f[4][2];                     // [mt][kh]
    float x0v[4];
    #pragma unroll
    for (int mt = 0; mt < 4; mt++) {
        const int m = mbase + mt * 32 + ln31;
        const float2 xy = ((const float2*)x)[m];   // coalesced 8B
        x0v[mt] = xy.x;
        #pragma unroll
        for (int kh = 0; kh < 2; kh++)
            #pragma unroll
            for (int j = 0; j < 8; j++) {
                const float d = (0.001f + (kh * 16 + hi * 8 + j) * gstep) - xy.y;
                k1f[mt][kh][j] = (_Float16)__expf(-inv * d * d);
            }
    }

    floatx16 acc[4][2];                  // [mt][nt]
    #pragma unroll
    for (int mt = 0; mt < 4; mt++)
        #pragma unroll
        for (int nt = 0; nt < 2; nt++)
            #pragma unroll
            for (int r = 0; r < 16; r++)
                acc[mt][nt][r] = 0.0f;

#define PSTEP(F00, F01, F10, F11, P)                                          \
    do {                                                                      \
        const float gp = 0.001f + (P) * gstep;                                \
        _Pragma("unroll")                                                     \
        for (int mt = 0; mt < 4; mt++) {                                      \
            const float d = gp - x0v[mt];                                     \
            const _Float16 k0 = (_Float16)__expf(-inv * d * d);               \
            const half8 a0 = k1f[mt][0] * k0;    /* shared by nt=0,1 */       \
            const half8 a1 = k1f[mt][1] * k0;                                 \
            acc[mt][0] = __builtin_amdgcn_mfma_f32_32x32x16_f16(              \
                a0, F00, acc[mt][0], 0, 0, 0);                                \
            acc[mt][0] = __builtin_amdgcn_mfma_f32_32x32x16_f16(              \
                a1, F01, acc[mt][0], 0, 0, 0);                                \
            acc[mt][1] = __builtin_amdgcn_mfma_f32_32x32x16_f16(              \
                a0, F10, acc[mt][1], 0, 0, 0);                                \
            acc[mt][1] = __builtin_amdgcn_mfma_f32_32x32x16_f16(              \
                a1, F11, acc[mt][1], 0, 0, 0);                                \
        }                                                                     \
    } while (0)

    // ---- K-loop: unrolled pairs, 2-deep static prefetch rotation ----
    #pragma unroll
    for (int pp = 0; pp < PDIM; pp += 2) {
        {   // p = pp : consume bA*, prefetch pp+2
            const half8 f00 = bA00, f01 = bA01, f10 = bA10, f11 = bA11;
            if (pp + 2 < PDIM) {
                bA00 = *(const half8*)(gB + (pp + 2) * PSTR);
                bA01 = *(const half8*)(gB + (pp + 2) * PSTR + 512);
                bA10 = *(const half8*)(gB + (pp + 2) * PSTR + 1024);
                bA11 = *(const half8*)(gB + (pp + 2) * PSTR + 1536);
            }
            PSTEP(f00, f01, f10, f11, pp);
        }
        {   // p = pp+1 : consume bB*, prefetch pp+3
            const half8 f00 = bB00, f01 = bB01, f10 = bB10, f11 = bB11;
            if (pp + 3 < PDIM) {
                bB00 = *(const half8*)(gB + (pp + 3) * PSTR);
                bB01 = *(const half8*)(gB + (pp + 3) * PSTR + 512);
                bB10 = *(const half8*)(gB + (pp + 3) * PSTR + 1024);
                bB11 = *(const half8*)(gB + (pp + 3) * PSTR + 1536);
            }
            PSTEP(f00, f01, f10, f11, pp + 1);
        }
    }
#undef PSTEP

    // ---- epilogue: C/D (32x32): col = lane&31, row = (r&3)+8*(r>>2)+4*hi.
    // Each store: 32 consecutive cols x 4B = a full 128B line. ----
    #pragma unroll
    for (int mt = 0; mt < 4; mt++) {
        const int row0 = mbase + mt * 32 + 4 * hi;
        #pragma unroll
        for (int nt = 0; nt < 2; nt++) {
            const int col = (fh * 2 + nt) * 32 + ln31;
            #pragma unroll
            for (int r = 0; r < 16; r++) {
                const int row = row0 + (r & 3) + 8 * (r >> 2);
                __builtin_nontemporal_store(acc[mt][nt][r],
                                            out + (size_t)row * FDIM + col);
            }
        }
    }
}

// ---------------------------------------------------------------------------
extern "C" void kernel_launch(void* const* d_in, const int* in_sizes, int n_in,
                              void* d_out, int out_size, void* d_ws, size_t ws_size,
                              hipStream_t stream) {
    const float* x     = (const float*)d_in[0];   // [8,16384,2]
    const float* sigma = (const float*)d_in[1];   // [1]
    const float* IF    = (const float*)d_in[2];   // [128,28,28]
    float* out = (float*)d_out;                   // [8,16384,128] fp32

    // d_ws: IFt f16 [28][4096] = 229376 bytes
    _Float16* IFt = (_Float16*)d_ws;

    prep_ift<<<(PDIM * PSTR) / 256, 256, 0, stream>>>(IF, IFt);      // 448 blocks
    // 256 chunks of 512 points x 2 feature halves = 512 blocks of 4 waves,
    // all 4 waves of a block share one fh -> B slabs shared in L1;
    // 2 blocks/CU, fully resident, single round.
    feats_kernel<<<(MPTS / 512) * 2, 256, 0, stream>>>(x, sigma, IFt, out);
}